// Round 1
// baseline (1514.110 us; speedup 1.0000x reference)
//
#include <hip/hip_runtime.h>
#include <hip/hip_bf16.h>

// Problem constants (fixed by the reference): B=8, S=2048, IN=4096, OUT=4096
#define M_TOT 16384
#define N_TOT 4096
#define K_TOT 4096
#define NELEM 16777216   // OUT*IN = 2^24 (index fits in 24 bits)

typedef __attribute__((ext_vector_type(8))) short bf16x8;
typedef __attribute__((ext_vector_type(4))) float f32x4;

#define AS1 __attribute__((address_space(1)))
#define AS3 __attribute__((address_space(3)))

struct SelState {
  unsigned long long prefix;   // accumulated high key bits
  unsigned long long thr;      // selection predicate: key <= thr
  unsigned int k_rem;
  unsigned int done;
  unsigned int active;
};

struct Ctl {
  unsigned long long pcount;   // mask popcount for dtype detection
  unsigned int mask_is_byte;
  SelState d;                  // drop selection state
  SelState g;                  // grow selection state
};

__device__ Ctl g_ctl;
__device__ unsigned int g_hist[4096];
__device__ unsigned char g_elig[NELEM];          // 1 = slot is OFF after drop (eligible to grow)
__device__ unsigned short g_wb[NELEM];           // masked weight, bf16 bits [OUT][IN]
__device__ unsigned short g_xb[(size_t)M_TOT * K_TOT]; // x, bf16 bits [M][K]

__device__ __forceinline__ unsigned short f2bf(float f) {
  unsigned int u = __float_as_uint(f);
  unsigned int r = (u + 0x7FFFu + ((u >> 16) & 1u)) >> 16;   // RNE
  return (unsigned short)r;
}

// 56-bit keys. Nonnegative floats: bit pattern order == value order.
__device__ __forceinline__ unsigned long long key_drop(const float* w, int i) {
  unsigned int b = __float_as_uint(w[i]) & 0x7FFFFFFFu;
  return (((unsigned long long)b) << 24) | (unsigned int)i;   // smallest |w|, lowest idx first
}
__device__ __forceinline__ unsigned long long key_grow(const float* g, int i) {
  unsigned int b = __float_as_uint(g[i]) & 0x7FFFFFFFu;
  b = ~b;                                                     // descending |grad|
  return (((unsigned long long)b) << 24) | (unsigned int)i;   // largest |g|, lowest idx first
}

__global__ void ctl_reset() {
  int t = threadIdx.x;
  if (t == 0) g_ctl.pcount = 0ull;
  for (int i = t; i < 4096; i += 256) g_hist[i] = 0;
}

// Detect mask dtype: read first NELEM bytes as u32 words (safe under both
// interpretations). bytes(bool): popcnt ~= 2.18M ; int32: popcnt ~= 545K.
__global__ void mask_popcnt(const unsigned int* mw) {
  const int NW = NELEM / 4;
  unsigned int s = 0;
  for (int i = blockIdx.x * blockDim.x + threadIdx.x; i < NW; i += gridDim.x * blockDim.x)
    s += __popc(mw[i]);
  for (int off = 32; off > 0; off >>= 1) s += __shfl_down(s, off, 64);
  if ((threadIdx.x & 63) == 0)
    atomicAdd((unsigned long long*)&g_ctl.pcount, (unsigned long long)s);
}

__global__ void sel_init(const int* ndp) {
  unsigned int k = (unsigned int)ndp[0];
  g_ctl.mask_is_byte = (g_ctl.pcount > 1200000ull) ? 1u : 0u;
  SelState s;
  s.prefix = 0ull; s.thr = 0ull; s.k_rem = k;
  s.done = (k == 0u) ? 1u : 0u;
  s.active = (k > 0u) ? 1u : 0u;
  g_ctl.d = s;
  g_ctl.g = s;
}

// Histogram of key bit-slice [shift, shift+nbits), restricted to prefix match.
template <int SEL>
__global__ __launch_bounds__(256) void hist_pass(const float* __restrict__ src, int shift, int nbits) {
  SelState& st = SEL ? g_ctl.g : g_ctl.d;
  if (st.done) return;
  __shared__ unsigned int lh[4096];
  const int nb = 1 << nbits;
  for (int i = threadIdx.x; i < nb; i += blockDim.x) lh[i] = 0;
  __syncthreads();
  const unsigned long long pref = st.prefix;
  for (int i = blockIdx.x * blockDim.x + threadIdx.x; i < NELEM; i += gridDim.x * blockDim.x) {
    if (SEL && !g_elig[i]) continue;
    unsigned long long key = SEL ? key_grow(src, i) : key_drop(src, i);
    if ((key >> (shift + nbits)) == pref)
      atomicAdd(&lh[(unsigned int)(key >> shift) & (unsigned int)(nb - 1)], 1u);
  }
  __syncthreads();
  for (int i = threadIdx.x; i < nb; i += blockDim.x)
    if (lh[i]) atomicAdd(&g_hist[i], lh[i]);
}

// Single-block: find the bin containing the k_rem-th element, update state,
// zero the histogram for the next pass.
template <int SEL>
__global__ void select_pass(int shift, int nbits) {
  SelState& st = SEL ? g_ctl.g : g_ctl.d;
  if (st.done) return;   // hist untouched (stays zero) when done
  __shared__ unsigned int sc[256];
  __shared__ int tgt;
  const int nb = 1 << nbits;
  const int per = (nb + 255) / 256;
  const int t = threadIdx.x;
  unsigned int s = 0;
  for (int j = 0; j < per; ++j) {
    int b = t * per + j;
    if (b < nb) s += g_hist[b];
  }
  sc[t] = s;
  __syncthreads();
  for (int off = 1; off < 256; off <<= 1) {   // inclusive scan
    unsigned int v = (t >= off) ? sc[t - off] : 0u;
    __syncthreads();
    sc[t] += v;
    __syncthreads();
  }
  const unsigned int k = st.k_rem;
  const unsigned int cum = sc[t];
  const unsigned int before = cum - s;
  if (before < k && k <= cum) tgt = t;   // exactly one thread matches
  __syncthreads();
  if (t == tgt) {
    unsigned int c = before;
    for (int j = 0; j < per; ++j) {
      int b = t * per + j;
      unsigned int h = (b < nb) ? g_hist[b] : 0u;
      if (c + h >= k) {
        unsigned long long np = (st.prefix << nbits) | (unsigned long long)(unsigned int)b;
        st.prefix = np;
        st.k_rem = k - c;
        st.thr = ((np + 1ull) << shift) - 1ull;   // all keys with this prefix or less
        if (k - c == h) st.done = 1;              // k-th is the max of this bin: exact
        break;
      }
      c += h;
    }
  }
  __syncthreads();
  for (int b = t; b < nb; b += 256) g_hist[b] = 0;
}

// eligible (grow candidate) = slot OFF after drop = !mask || dropped
__global__ __launch_bounds__(256) void build_elig(const float* __restrict__ w, const void* maskp) {
  int i = blockIdx.x * blockDim.x + threadIdx.x;
  if (i >= NELEM) return;
  bool m = g_ctl.mask_is_byte ? (((const unsigned char*)maskp)[i] != 0)
                              : (((const int*)maskp)[i] != 0);
  bool dropped = g_ctl.d.active && (key_drop(w, i) <= g_ctl.d.thr);
  g_elig[i] = (!m || dropped) ? 1 : 0;
}

// final mask: kept (= !elig) OR grown (elig && grow-key selected); emit bf16 W
__global__ __launch_bounds__(256) void build_wb(const float* __restrict__ w, const float* __restrict__ gr) {
  int i = blockIdx.x * blockDim.x + threadIdx.x;
  if (i >= NELEM) return;
  bool keep;
  if (!g_elig[i]) keep = true;
  else keep = g_ctl.g.active && (key_grow(gr, i) <= g_ctl.g.thr);
  g_wb[i] = keep ? f2bf(w[i]) : (unsigned short)0;
}

__global__ __launch_bounds__(256) void convert_x(const float* __restrict__ x) {
  int i = blockIdx.x * blockDim.x + threadIdx.x;   // over float4 quads
  float4 v = ((const float4*)x)[i];
  ushort4 o;
  o.x = f2bf(v.x); o.y = f2bf(v.y); o.z = f2bf(v.z); o.w = f2bf(v.w);
  ((ushort4*)g_xb)[i] = o;
}

// ---- GEMM: C[m][n] = sum_k X[m][k] * W[n][k], bf16 inputs, fp32 out ----
// 128x128 tile, BK=64, 4 waves (2x2 of 64x64), 16x16x32 MFMA, m97-style
// single-buffer 2-barrier loop with global_load_lds width=16.
#define BM 128
#define BN 128
#define BKK 64

__global__ __launch_bounds__(256) void gemm_kernel(float* __restrict__ out) {
  __shared__ unsigned short As[BM][BKK];   // 16 KB, row-major K-contiguous
  __shared__ unsigned short Bs[BN][BKK];   // 16 KB
  const int tid = threadIdx.x;
  const int lane = tid & 63;
  const int w = tid >> 6;
  const int gm0 = blockIdx.y * BM;
  const int gn0 = blockIdx.x * BN;
  const int wr = w >> 1, wc = w & 1;

  f32x4 acc[4][4];
#pragma unroll
  for (int a = 0; a < 4; ++a)
#pragma unroll
    for (int b = 0; b < 4; ++b)
      acc[a][b] = (f32x4){0.f, 0.f, 0.f, 0.f};

  // staging: wave w owns rows [w*32, w*32+32) of each tile.
  // one global_load_lds(16B): 64 lanes * 16B = 1KB = 8 rows of 64 bf16.
  const int srow = w * 32 + (lane >> 3);
  const int scol = (lane & 7) * 8;
  const unsigned short* Ag = g_xb + (size_t)(gm0 + srow) * K_TOT + scol;
  const unsigned short* Bg = g_wb + (size_t)(gn0 + srow) * K_TOT + scol;

  for (int kt = 0; kt < K_TOT; kt += BKK) {
    __syncthreads();   // previous iter's compute done before overwrite
#pragma unroll
    for (int j = 0; j < 4; ++j) {
      __builtin_amdgcn_global_load_lds(
          (const AS1 void*)(Ag + kt + (size_t)j * 8 * K_TOT),
          (AS3 void*)(&As[w * 32 + j * 8][0]), 16, 0, 0);
      __builtin_amdgcn_global_load_lds(
          (const AS1 void*)(Bg + kt + (size_t)j * 8 * K_TOT),
          (AS3 void*)(&Bs[w * 32 + j * 8][0]), 16, 0, 0);
    }
    __syncthreads();   // compiler drains vmcnt before barrier -> tiles ready

    const int kc = (lane >> 4) * 8;   // k-chunk within K=32 fragment
    const int r16 = lane & 15;
#pragma unroll
    for (int kk = 0; kk < 2; ++kk) {
      bf16x8 af[4], bfr[4];
#pragma unroll
      for (int mi = 0; mi < 4; ++mi)
        af[mi] = *(const bf16x8*)&As[wr * 64 + mi * 16 + r16][kk * 32 + kc];
#pragma unroll
      for (int ni = 0; ni < 4; ++ni)
        bfr[ni] = *(const bf16x8*)&Bs[wc * 64 + ni * 16 + r16][kk * 32 + kc];
#pragma unroll
      for (int mi = 0; mi < 4; ++mi)
#pragma unroll
        for (int ni = 0; ni < 4; ++ni)
          acc[mi][ni] = __builtin_amdgcn_mfma_f32_16x16x32_bf16(
              af[mi], bfr[ni], acc[mi][ni], 0, 0, 0);
    }
  }

  // C/D layout (m89-verified): col = lane&15, row = (lane>>4)*4 + reg
  const int cn = gn0 + wc * 64 + (lane & 15);
  const int rm = gm0 + wr * 64 + (lane >> 4) * 4;
#pragma unroll
  for (int mi = 0; mi < 4; ++mi)
#pragma unroll
    for (int ni = 0; ni < 4; ++ni)
#pragma unroll
      for (int r = 0; r < 4; ++r)
        out[(size_t)(rm + mi * 16 + r) * N_TOT + (cn + ni * 16)] = acc[mi][ni][r];
}

extern "C" void kernel_launch(void* const* d_in, const int* in_sizes, int n_in,
                              void* d_out, int out_size, void* d_ws, size_t ws_size,
                              hipStream_t stream) {
  const float* x  = (const float*)d_in[0];
  const float* wt = (const float*)d_in[1];
  const float* gr = (const float*)d_in[2];
  const void*  mk = d_in[3];
  const int*   nd = (const int*)d_in[4];
  (void)d_ws; (void)ws_size; (void)in_sizes; (void)n_in; (void)out_size;

  ctl_reset<<<1, 256, 0, stream>>>();
  mask_popcnt<<<512, 256, 0, stream>>>((const unsigned int*)mk);
  sel_init<<<1, 1, 0, stream>>>(nd);

  const int shifts[5] = {44, 32, 24, 12, 0};
  const int nbits[5]  = {12, 12, 8, 12, 12};

  for (int p = 0; p < 5; ++p) {   // drop: k smallest |w| (global)
    hist_pass<0><<<1024, 256, 0, stream>>>(wt, shifts[p], nbits[p]);
    select_pass<0><<<1, 256, 0, stream>>>(shifts[p], nbits[p]);
  }
  build_elig<<<NELEM / 256, 256, 0, stream>>>(wt, mk);
  for (int p = 0; p < 5; ++p) {   // grow: k largest |grad| among eligible
    hist_pass<1><<<1024, 256, 0, stream>>>(gr, shifts[p], nbits[p]);
    select_pass<1><<<1, 256, 0, stream>>>(shifts[p], nbits[p]);
  }
  build_wb<<<NELEM / 256, 256, 0, stream>>>(wt, gr);
  convert_x<<<(M_TOT * K_TOT / 4) / 256, 256, 0, stream>>>(x);
  gemm_kernel<<<dim3(N_TOT / BN, M_TOT / BM), 256, 0, stream>>>((float*)d_out);
}

// Round 2
// 1106.437 us; speedup vs baseline: 1.3685x; 1.3685x over previous
//
#include <hip/hip_runtime.h>
#include <hip/hip_bf16.h>

// Problem constants (fixed by the reference): B=8, S=2048, IN=4096, OUT=4096
#define M_TOT 16384
#define N_TOT 4096
#define K_TOT 4096
#define NELEM 16777216   // OUT*IN = 2^24 (index fits in 24 bits)

typedef __attribute__((ext_vector_type(8))) short bf16x8;
typedef __attribute__((ext_vector_type(4))) float f32x4;

#define AS1 __attribute__((address_space(1)))
#define AS3 __attribute__((address_space(3)))

struct SelState {
  unsigned long long prefix;   // accumulated high key bits
  unsigned long long thr;      // selection predicate: key <= thr
  unsigned int k_rem;
  unsigned int done;
  unsigned int active;
};

struct Ctl {
  unsigned long long pcount;   // mask popcount for dtype detection
  unsigned int mask_is_byte;
  SelState d;                  // drop selection state
  SelState g;                  // grow selection state
};

__device__ Ctl g_ctl;
__device__ unsigned int g_hist[4096];
__device__ unsigned char g_elig[NELEM];          // 1 = slot OFF after drop (grow candidate)
__device__ unsigned short g_wb[NELEM];           // masked weight, bf16 bits [OUT][IN]
__device__ unsigned short g_xb[(size_t)M_TOT * K_TOT]; // x, bf16 bits [M][K]

__device__ __forceinline__ unsigned short f2bf(float f) {
  unsigned int u = __float_as_uint(f);
  unsigned int r = (u + 0x7FFFu + ((u >> 16) & 1u)) >> 16;   // RNE
  return (unsigned short)r;
}

// 56-bit keys. Nonnegative floats: bit pattern order == value order.
__device__ __forceinline__ unsigned long long key_drop_bits(unsigned int fb, int i) {
  unsigned int b = fb & 0x7FFFFFFFu;
  return (((unsigned long long)b) << 24) | (unsigned int)i;   // smallest |w|, lowest idx first
}
__device__ __forceinline__ unsigned long long key_grow_bits(unsigned int fb, int i) {
  unsigned int b = ~(fb & 0x7FFFFFFFu);                       // descending |grad|
  return (((unsigned long long)b) << 24) | (unsigned int)i;   // largest |g|, lowest idx first
}

__global__ void ctl_reset() {
  int t = threadIdx.x;
  if (t == 0) g_ctl.pcount = 0ull;
  for (int i = t; i < 4096; i += 256) g_hist[i] = 0;
}

// Detect mask dtype: read first NELEM bytes as u32 words (safe under both
// interpretations). bytes(bool): popcnt ~= 2.18M ; int32: popcnt ~= 545K.
__global__ void mask_popcnt(const unsigned int* mw) {
  const int NW = NELEM / 4;
  unsigned int s = 0;
  for (int i = blockIdx.x * blockDim.x + threadIdx.x; i < NW; i += gridDim.x * blockDim.x)
    s += __popc(mw[i]);
  for (int off = 32; off > 0; off >>= 1) s += __shfl_down(s, off, 64);
  if ((threadIdx.x & 63) == 0)
    atomicAdd((unsigned long long*)&g_ctl.pcount, (unsigned long long)s);
}

__global__ void sel_init(const int* ndp) {
  unsigned int k = (unsigned int)ndp[0];
  g_ctl.mask_is_byte = (g_ctl.pcount > 1200000ull) ? 1u : 0u;
  SelState s;
  s.prefix = 0ull; s.thr = 0ull; s.k_rem = k;
  s.done = (k == 0u) ? 1u : 0u;
  s.active = (k > 0u) ? 1u : 0u;
  g_ctl.d = s;
  g_ctl.g = s;
}

// Histogram of key bit-slice [shift, shift+nbits), restricted to prefix match.
// float4-vectorized: 4 elements/thread/iter.
template <int SEL>
__global__ __launch_bounds__(256) void hist_pass(const float* __restrict__ src, int shift, int nbits) {
  SelState& st = SEL ? g_ctl.g : g_ctl.d;
  if (st.done) return;
  __shared__ unsigned int lh[4096];
  const int nb = 1 << nbits;
  for (int i = threadIdx.x; i < nb; i += blockDim.x) lh[i] = 0;
  __syncthreads();
  const unsigned long long pref = st.prefix;
  const int N4 = NELEM / 4;
  for (int q = blockIdx.x * blockDim.x + threadIdx.x; q < N4; q += gridDim.x * blockDim.x) {
    float4 v = ((const float4*)src)[q];
    float fv[4] = {v.x, v.y, v.z, v.w};
    uchar4 e4;
    unsigned char ev[4] = {1, 1, 1, 1};
    if (SEL) {
      e4 = ((const uchar4*)g_elig)[q];
      ev[0] = e4.x; ev[1] = e4.y; ev[2] = e4.z; ev[3] = e4.w;
    }
#pragma unroll
    for (int j = 0; j < 4; ++j) {
      if (SEL && !ev[j]) continue;
      int i = q * 4 + j;
      unsigned int fb = __float_as_uint(fv[j]);
      unsigned long long key = SEL ? key_grow_bits(fb, i) : key_drop_bits(fb, i);
      if ((key >> (shift + nbits)) == pref)
        atomicAdd(&lh[(unsigned int)(key >> shift) & (unsigned int)(nb - 1)], 1u);
    }
  }
  __syncthreads();
  for (int i = threadIdx.x; i < nb; i += blockDim.x)
    if (lh[i]) atomicAdd(&g_hist[i], lh[i]);
}

// Single-block: find the bin containing the k_rem-th element, update state,
// zero the histogram for the next pass.
template <int SEL>
__global__ void select_pass(int shift, int nbits) {
  SelState& st = SEL ? g_ctl.g : g_ctl.d;
  if (st.done) return;   // hist untouched (stays zero) when done
  __shared__ unsigned int sc[256];
  __shared__ int tgt;
  const int nb = 1 << nbits;
  const int per = (nb + 255) / 256;
  const int t = threadIdx.x;
  unsigned int s = 0;
  for (int j = 0; j < per; ++j) {
    int b = t * per + j;
    if (b < nb) s += g_hist[b];
  }
  sc[t] = s;
  __syncthreads();
  for (int off = 1; off < 256; off <<= 1) {   // inclusive scan
    unsigned int v = (t >= off) ? sc[t - off] : 0u;
    __syncthreads();
    sc[t] += v;
    __syncthreads();
  }
  const unsigned int k = st.k_rem;
  const unsigned int cum = sc[t];
  const unsigned int before = cum - s;
  if (before < k && k <= cum) tgt = t;   // exactly one thread matches
  __syncthreads();
  if (t == tgt) {
    unsigned int c = before;
    for (int j = 0; j < per; ++j) {
      int b = t * per + j;
      unsigned int h = (b < nb) ? g_hist[b] : 0u;
      if (c + h >= k) {
        unsigned long long np = (st.prefix << nbits) | (unsigned long long)(unsigned int)b;
        st.prefix = np;
        st.k_rem = k - c;
        st.thr = ((np + 1ull) << shift) - 1ull;   // all keys with this prefix or less
        if (k - c == h) st.done = 1;              // k-th is the max of this bin: exact
        break;
      }
      c += h;
    }
  }
  __syncthreads();
  for (int b = t; b < nb; b += 256) g_hist[b] = 0;
}

// eligible (grow candidate) = slot OFF after drop = !mask || dropped. 4/thread.
__global__ __launch_bounds__(256) void build_elig(const float* __restrict__ w, const void* maskp) {
  int q = blockIdx.x * blockDim.x + threadIdx.x;   // over quads
  if (q >= NELEM / 4) return;
  float4 wv = ((const float4*)w)[q];
  float fv[4] = {wv.x, wv.y, wv.z, wv.w};
  unsigned char m[4];
  if (g_ctl.mask_is_byte) {
    uchar4 m4 = ((const uchar4*)maskp)[q];
    m[0] = m4.x; m[1] = m4.y; m[2] = m4.z; m[3] = m4.w;
  } else {
    int4 m4 = ((const int4*)maskp)[q];
    m[0] = m4.x != 0; m[1] = m4.y != 0; m[2] = m4.z != 0; m[3] = m4.w != 0;
  }
  const bool act = g_ctl.d.active;
  const unsigned long long thr = g_ctl.d.thr;
  uchar4 e;
  unsigned char ev[4];
#pragma unroll
  for (int j = 0; j < 4; ++j) {
    int i = q * 4 + j;
    bool dropped = act && (key_drop_bits(__float_as_uint(fv[j]), i) <= thr);
    ev[j] = (!m[j] || dropped) ? 1 : 0;
  }
  e.x = ev[0]; e.y = ev[1]; e.z = ev[2]; e.w = ev[3];
  ((uchar4*)g_elig)[q] = e;
}

// final mask: kept (= !elig) OR grown (elig && grow-key selected); emit bf16 W
__global__ __launch_bounds__(256) void build_wb(const float* __restrict__ w, const float* __restrict__ gr) {
  int q = blockIdx.x * blockDim.x + threadIdx.x;
  if (q >= NELEM / 4) return;
  float4 wv = ((const float4*)w)[q];
  float4 gv = ((const float4*)gr)[q];
  float wf[4] = {wv.x, wv.y, wv.z, wv.w};
  float gf[4] = {gv.x, gv.y, gv.z, gv.w};
  uchar4 e4 = ((const uchar4*)g_elig)[q];
  unsigned char ev[4] = {e4.x, e4.y, e4.z, e4.w};
  const bool act = g_ctl.g.active;
  const unsigned long long thr = g_ctl.g.thr;
  ushort4 o;
  unsigned short ov[4];
#pragma unroll
  for (int j = 0; j < 4; ++j) {
    int i = q * 4 + j;
    bool keep;
    if (!ev[j]) keep = true;
    else keep = act && (key_grow_bits(__float_as_uint(gf[j]), i) <= thr);
    ov[j] = keep ? f2bf(wf[j]) : (unsigned short)0;
  }
  o.x = ov[0]; o.y = ov[1]; o.z = ov[2]; o.w = ov[3];
  ((ushort4*)g_wb)[q] = o;
}

__global__ __launch_bounds__(256) void convert_x(const float* __restrict__ x) {
  int i = blockIdx.x * blockDim.x + threadIdx.x;   // over float4 quads
  float4 v = ((const float4*)x)[i];
  ushort4 o;
  o.x = f2bf(v.x); o.y = f2bf(v.y); o.z = f2bf(v.z); o.w = f2bf(v.w);
  ((ushort4*)g_xb)[i] = o;
}

// ---- GEMM: C[m][n] = sum_k X[m][k] * W[n][k], bf16 inputs, fp32 out ----
// 128x128 tile, BK=64, 4 waves (2x2 of 64x64), 16x16x32 MFMA.
// LDS XOR-swizzle (T2, rule #21): global_load_lds writes linearly, so the
// per-lane GLOBAL source column is pre-swizzled (scol = 16B*((lane&7)^(lane>>3)),
// valid because row&7 == lane>>3 during staging), and every fragment read
// XORs its byte column with ((row&7)<<4). Net effect: element (row,col) lives
// at LDS byte row*128 + ((col*2) ^ ((row&7)<<4)). A wave64 ds_read_b128 then
// hits all 8 16B slots with 8 lanes each -> all 32 banks balanced (structural
// minimum), vs. the unswizzled 16-way conflict on a 4-bank cluster.
#define BM 128
#define BN 128
#define BKK 64
#define ROWB (BKK * 2)   // 128 bytes per LDS row

__global__ __launch_bounds__(256) void gemm_kernel(float* __restrict__ out) {
  __shared__ unsigned short As[BM][BKK];   // 16 KB
  __shared__ unsigned short Bs[BN][BKK];   // 16 KB
  const int tid = threadIdx.x;
  const int lane = tid & 63;
  const int w = tid >> 6;
  const int gm0 = blockIdx.y * BM;
  const int gn0 = blockIdx.x * BN;
  const int wr = w >> 1, wc = w & 1;

  f32x4 acc[4][4];
#pragma unroll
  for (int a = 0; a < 4; ++a)
#pragma unroll
    for (int b = 0; b < 4; ++b)
      acc[a][b] = (f32x4){0.f, 0.f, 0.f, 0.f};

  // staging: wave w owns rows [w*32, w*32+32). One global_load_lds(16B):
  // 64 lanes * 16B = 1KB = 8 rows. Source column pre-swizzled per lane.
  const int srow = w * 32 + (lane >> 3);
  const int scol = 8 * ((lane & 7) ^ (lane >> 3));   // elements (16B units /2)
  const unsigned short* Ag = g_xb + (size_t)(gm0 + srow) * K_TOT + scol;
  const unsigned short* Bg = g_wb + (size_t)(gn0 + srow) * K_TOT + scol;

  const int r16 = lane & 15;
  const int xv = (r16 & 7) << 4;            // read-side XOR
  const int cb = (lane >> 4) << 4;          // 16B column slot within 64B half
  const char* Ab = (const char*)As + (wr * 64 + r16) * ROWB;
  const char* Bb = (const char*)Bs + (wc * 64 + r16) * ROWB;

  for (int kt = 0; kt < K_TOT; kt += BKK) {
    __syncthreads();   // previous iter's compute done before overwrite
#pragma unroll
    for (int j = 0; j < 4; ++j) {
      __builtin_amdgcn_global_load_lds(
          (const AS1 void*)(Ag + kt + (size_t)j * 8 * K_TOT),
          (AS3 void*)(&As[w * 32 + j * 8][0]), 16, 0, 0);
      __builtin_amdgcn_global_load_lds(
          (const AS1 void*)(Bg + kt + (size_t)j * 8 * K_TOT),
          (AS3 void*)(&Bs[w * 32 + j * 8][0]), 16, 0, 0);
    }
    __syncthreads();   // compiler drains vmcnt before barrier -> tiles ready

#pragma unroll
    for (int kk = 0; kk < 2; ++kk) {
      bf16x8 af[4], bfr[4];
#pragma unroll
      for (int mi = 0; mi < 4; ++mi)
        af[mi] = *(const bf16x8*)(Ab + mi * 16 * ROWB + (((kk << 6) | cb) ^ xv));
#pragma unroll
      for (int ni = 0; ni < 4; ++ni)
        bfr[ni] = *(const bf16x8*)(Bb + ni * 16 * ROWB + (((kk << 6) | cb) ^ xv));
#pragma unroll
      for (int mi = 0; mi < 4; ++mi)
#pragma unroll
        for (int ni = 0; ni < 4; ++ni)
          acc[mi][ni] = __builtin_amdgcn_mfma_f32_16x16x32_bf16(
              af[mi], bfr[ni], acc[mi][ni], 0, 0, 0);
    }
  }

  // C/D layout (m89-verified): col = lane&15, row = (lane>>4)*4 + reg
  const int cn = gn0 + wc * 64 + (lane & 15);
  const int rm = gm0 + wr * 64 + (lane >> 4) * 4;
#pragma unroll
  for (int mi = 0; mi < 4; ++mi)
#pragma unroll
    for (int ni = 0; ni < 4; ++ni)
#pragma unroll
      for (int r = 0; r < 4; ++r)
        out[(size_t)(rm + mi * 16 + r) * N_TOT + (cn + ni * 16)] = acc[mi][ni][r];
}

extern "C" void kernel_launch(void* const* d_in, const int* in_sizes, int n_in,
                              void* d_out, int out_size, void* d_ws, size_t ws_size,
                              hipStream_t stream) {
  const float* x  = (const float*)d_in[0];
  const float* wt = (const float*)d_in[1];
  const float* gr = (const float*)d_in[2];
  const void*  mk = d_in[3];
  const int*   nd = (const int*)d_in[4];
  (void)d_ws; (void)ws_size; (void)in_sizes; (void)n_in; (void)out_size;

  ctl_reset<<<1, 256, 0, stream>>>();
  mask_popcnt<<<512, 256, 0, stream>>>((const unsigned int*)mk);
  sel_init<<<1, 1, 0, stream>>>(nd);

  const int shifts[5] = {44, 32, 24, 12, 0};
  const int nbits[5]  = {12, 12, 8, 12, 12};

  for (int p = 0; p < 5; ++p) {   // drop: k smallest |w| (global)
    hist_pass<0><<<1024, 256, 0, stream>>>(wt, shifts[p], nbits[p]);
    select_pass<0><<<1, 256, 0, stream>>>(shifts[p], nbits[p]);
  }
  build_elig<<<NELEM / 4 / 256, 256, 0, stream>>>(wt, mk);
  for (int p = 0; p < 5; ++p) {   // grow: k largest |grad| among eligible
    hist_pass<1><<<1024, 256, 0, stream>>>(gr, shifts[p], nbits[p]);
    select_pass<1><<<1, 256, 0, stream>>>(shifts[p], nbits[p]);
  }
  build_wb<<<NELEM / 4 / 256, 256, 0, stream>>>(wt, gr);
  convert_x<<<(M_TOT * K_TOT / 4) / 256, 256, 0, stream>>>(x);
  gemm_kernel<<<dim3(N_TOT / BN, M_TOT / BM), 256, 0, stream>>>((float*)d_out);
}

// Round 3
// 1084.422 us; speedup vs baseline: 1.3962x; 1.0203x over previous
//
#include <hip/hip_runtime.h>
#include <hip/hip_bf16.h>

// Problem constants (fixed by the reference): B=8, S=2048, IN=4096, OUT=4096
#define M_TOT 16384
#define N_TOT 4096
#define K_TOT 4096
#define NELEM 16777216   // OUT*IN = 2^24 (index fits in 24 bits)

typedef __attribute__((ext_vector_type(8))) short bf16x8;
typedef __attribute__((ext_vector_type(4))) float f32x4;

#define AS1 __attribute__((address_space(1)))
#define AS3 __attribute__((address_space(3)))

struct SelState {
  unsigned long long prefix;   // accumulated high key bits
  unsigned long long thr;      // selection predicate: key <= thr
  unsigned int k_rem;
  unsigned int done;
  unsigned int active;
};

struct Ctl {
  unsigned long long pcount;   // mask popcount for dtype detection
  unsigned int mask_is_byte;
  SelState d;                  // drop selection state
  SelState g;                  // grow selection state
};

__device__ Ctl g_ctl;
__device__ unsigned int g_hist[4096];
__device__ unsigned char g_elig[NELEM];          // 1 = slot OFF after drop (grow candidate)
__device__ unsigned short g_wb[NELEM];           // masked weight, bf16 bits [OUT][IN]
__device__ unsigned short g_xb[(size_t)M_TOT * K_TOT]; // x, bf16 bits [M][K]

__device__ __forceinline__ unsigned short f2bf(float f) {
  unsigned int u = __float_as_uint(f);
  unsigned int r = (u + 0x7FFFu + ((u >> 16) & 1u)) >> 16;   // RNE
  return (unsigned short)r;
}

// 56-bit keys. Nonnegative floats: bit pattern order == value order.
__device__ __forceinline__ unsigned long long key_drop_bits(unsigned int fb, int i) {
  unsigned int b = fb & 0x7FFFFFFFu;
  return (((unsigned long long)b) << 24) | (unsigned int)i;   // smallest |w|, lowest idx first
}
__device__ __forceinline__ unsigned long long key_grow_bits(unsigned int fb, int i) {
  unsigned int b = ~(fb & 0x7FFFFFFFu);                       // descending |grad|
  return (((unsigned long long)b) << 24) | (unsigned int)i;   // largest |g|, lowest idx first
}

__global__ void ctl_reset() {
  int t = threadIdx.x;
  if (t == 0) g_ctl.pcount = 0ull;
  for (int i = t; i < 4096; i += 256) g_hist[i] = 0;
}

// Detect mask dtype: read first NELEM bytes as u32 words (safe under both
// interpretations). bytes(bool): popcnt ~= 2.18M ; int32: popcnt ~= 545K.
__global__ void mask_popcnt(const unsigned int* mw) {
  const int NW = NELEM / 4;
  unsigned int s = 0;
  for (int i = blockIdx.x * blockDim.x + threadIdx.x; i < NW; i += gridDim.x * blockDim.x)
    s += __popc(mw[i]);
  for (int off = 32; off > 0; off >>= 1) s += __shfl_down(s, off, 64);
  if ((threadIdx.x & 63) == 0)
    atomicAdd((unsigned long long*)&g_ctl.pcount, (unsigned long long)s);
}

__global__ void sel_init(const int* ndp) {
  unsigned int k = (unsigned int)ndp[0];
  g_ctl.mask_is_byte = (g_ctl.pcount > 1200000ull) ? 1u : 0u;
  SelState s;
  s.prefix = 0ull; s.thr = 0ull; s.k_rem = k;
  s.done = (k == 0u) ? 1u : 0u;
  s.active = (k > 0u) ? 1u : 0u;
  g_ctl.d = s;
  g_ctl.g = s;
}

// Histogram of key bit-slice [shift, shift+nbits), restricted to prefix match.
// float4-vectorized: 4 elements/thread/iter.
template <int SEL>
__global__ __launch_bounds__(256) void hist_pass(const float* __restrict__ src, int shift, int nbits) {
  SelState& st = SEL ? g_ctl.g : g_ctl.d;
  if (st.done) return;
  __shared__ unsigned int lh[4096];
  const int nb = 1 << nbits;
  for (int i = threadIdx.x; i < nb; i += blockDim.x) lh[i] = 0;
  __syncthreads();
  const unsigned long long pref = st.prefix;
  const int N4 = NELEM / 4;
  for (int q = blockIdx.x * blockDim.x + threadIdx.x; q < N4; q += gridDim.x * blockDim.x) {
    float4 v = ((const float4*)src)[q];
    float fv[4] = {v.x, v.y, v.z, v.w};
    uchar4 e4;
    unsigned char ev[4] = {1, 1, 1, 1};
    if (SEL) {
      e4 = ((const uchar4*)g_elig)[q];
      ev[0] = e4.x; ev[1] = e4.y; ev[2] = e4.z; ev[3] = e4.w;
    }
#pragma unroll
    for (int j = 0; j < 4; ++j) {
      if (SEL && !ev[j]) continue;
      int i = q * 4 + j;
      unsigned int fb = __float_as_uint(fv[j]);
      unsigned long long key = SEL ? key_grow_bits(fb, i) : key_drop_bits(fb, i);
      if ((key >> (shift + nbits)) == pref)
        atomicAdd(&lh[(unsigned int)(key >> shift) & (unsigned int)(nb - 1)], 1u);
    }
  }
  __syncthreads();
  for (int i = threadIdx.x; i < nb; i += blockDim.x)
    if (lh[i]) atomicAdd(&g_hist[i], lh[i]);
}

// Single-block: find the bin containing the k_rem-th element, update state,
// zero the histogram for the next pass.
template <int SEL>
__global__ void select_pass(int shift, int nbits) {
  SelState& st = SEL ? g_ctl.g : g_ctl.d;
  if (st.done) return;   // hist untouched (stays zero) when done
  __shared__ unsigned int sc[256];
  __shared__ int tgt;
  const int nb = 1 << nbits;
  const int per = (nb + 255) / 256;
  const int t = threadIdx.x;
  unsigned int s = 0;
  for (int j = 0; j < per; ++j) {
    int b = t * per + j;
    if (b < nb) s += g_hist[b];
  }
  sc[t] = s;
  __syncthreads();
  for (int off = 1; off < 256; off <<= 1) {   // inclusive scan
    unsigned int v = (t >= off) ? sc[t - off] : 0u;
    __syncthreads();
    sc[t] += v;
    __syncthreads();
  }
  const unsigned int k = st.k_rem;
  const unsigned int cum = sc[t];
  const unsigned int before = cum - s;
  if (before < k && k <= cum) tgt = t;   // exactly one thread matches
  __syncthreads();
  if (t == tgt) {
    unsigned int c = before;
    for (int j = 0; j < per; ++j) {
      int b = t * per + j;
      unsigned int h = (b < nb) ? g_hist[b] : 0u;
      if (c + h >= k) {
        unsigned long long np = (st.prefix << nbits) | (unsigned long long)(unsigned int)b;
        st.prefix = np;
        st.k_rem = k - c;
        st.thr = ((np + 1ull) << shift) - 1ull;   // all keys with this prefix or less
        if (k - c == h) st.done = 1;              // k-th is the max of this bin: exact
        break;
      }
      c += h;
    }
  }
  __syncthreads();
  for (int b = t; b < nb; b += 256) g_hist[b] = 0;
}

// eligible (grow candidate) = slot OFF after drop = !mask || dropped. 4/thread.
__global__ __launch_bounds__(256) void build_elig(const float* __restrict__ w, const void* maskp) {
  int q = blockIdx.x * blockDim.x + threadIdx.x;   // over quads
  if (q >= NELEM / 4) return;
  float4 wv = ((const float4*)w)[q];
  float fv[4] = {wv.x, wv.y, wv.z, wv.w};
  unsigned char m[4];
  if (g_ctl.mask_is_byte) {
    uchar4 m4 = ((const uchar4*)maskp)[q];
    m[0] = m4.x; m[1] = m4.y; m[2] = m4.z; m[3] = m4.w;
  } else {
    int4 m4 = ((const int4*)maskp)[q];
    m[0] = m4.x != 0; m[1] = m4.y != 0; m[2] = m4.z != 0; m[3] = m4.w != 0;
  }
  const bool act = g_ctl.d.active;
  const unsigned long long thr = g_ctl.d.thr;
  uchar4 e;
  unsigned char ev[4];
#pragma unroll
  for (int j = 0; j < 4; ++j) {
    int i = q * 4 + j;
    bool dropped = act && (key_drop_bits(__float_as_uint(fv[j]), i) <= thr);
    ev[j] = (!m[j] || dropped) ? 1 : 0;
  }
  e.x = ev[0]; e.y = ev[1]; e.z = ev[2]; e.w = ev[3];
  ((uchar4*)g_elig)[q] = e;
}

// final mask: kept (= !elig) OR grown (elig && grow-key selected); emit bf16 W
__global__ __launch_bounds__(256) void build_wb(const float* __restrict__ w, const float* __restrict__ gr) {
  int q = blockIdx.x * blockDim.x + threadIdx.x;
  if (q >= NELEM / 4) return;
  float4 wv = ((const float4*)w)[q];
  float4 gv = ((const float4*)gr)[q];
  float wf[4] = {wv.x, wv.y, wv.z, wv.w};
  float gf[4] = {gv.x, gv.y, gv.z, gv.w};
  uchar4 e4 = ((const uchar4*)g_elig)[q];
  unsigned char ev[4] = {e4.x, e4.y, e4.z, e4.w};
  const bool act = g_ctl.g.active;
  const unsigned long long thr = g_ctl.g.thr;
  ushort4 o;
  unsigned short ov[4];
#pragma unroll
  for (int j = 0; j < 4; ++j) {
    int i = q * 4 + j;
    bool keep;
    if (!ev[j]) keep = true;
    else keep = act && (key_grow_bits(__float_as_uint(gf[j]), i) <= thr);
    ov[j] = keep ? f2bf(wf[j]) : (unsigned short)0;
  }
  o.x = ov[0]; o.y = ov[1]; o.z = ov[2]; o.w = ov[3];
  ((ushort4*)g_wb)[q] = o;
}

__global__ __launch_bounds__(256) void convert_x(const float* __restrict__ x) {
  int i = blockIdx.x * blockDim.x + threadIdx.x;   // over float4 quads
  float4 v = ((const float4*)x)[i];
  ushort4 o;
  o.x = f2bf(v.x); o.y = f2bf(v.y); o.z = f2bf(v.z); o.w = f2bf(v.w);
  ((ushort4*)g_xb)[i] = o;
}

// ---- GEMM: C[m][n] = sum_k X[m][k] * W[n][k], bf16 in, fp32 out ----
// 256x256 tile, BK=64, 512 threads = 8 waves (2M x 4N), per-wave 128x64 out.
// 8-phase schedule (T3+T4), counted vmcnt(4) at phases 4/8 only, setprio (T5),
// XOR-swizzled LDS (T2, round-2-verified pattern), XCD block swizzle (T1).
//
// Quadrant walk per K-tile: q00(A0,B0) -> q01(A0,B1) -> q11(A1,B1) -> q10(A1,B0).
// LDS reads: A at ph1,ph3; B at ph1,ph2 => B-halves free after ph2-end barrier,
// A-halves free after ph3-end. Stage schedule (tile T pair 2i,2i+1 per iter):
//   ph1: t(2i+1) A-h0   ph2: t(2i+1) A-h1   ph3: t(2i+2) B-h0  ph4: t(2i+2) B-h1
//   ph5: t(2i+2) A-h0   ph6: t(2i+2) A-h1   ph7: t(2i+3) B-h0  ph8: t(2i+3) B-h1
// vmcnt(4) at ph4-end proves tile 2i+1 landed (leaves 2 half-tiles in flight);
// vmcnt(4) at ph8-end proves tile 2i+2 landed. Barrier after vmcnt gives
// cross-wave visibility. Stage tile index wraps mod 64 past the end: same
// buffer parity, same hazard windows, keeps vmcnt counts exact.
#define BM2 256
#define BN2 256
#define BK2 64
#define NT2 (K_TOT / BK2)      // 64 K-tiles
#define BUFB (256 * 128)       // LDS bytes per buffer (256 rows x 128B)

__global__ __launch_bounds__(512, 2) void gemm_kernel(float* __restrict__ out) {
  __shared__ unsigned short As[2][BM2][BK2];   // 64 KB
  __shared__ unsigned short Bs[2][BN2][BK2];   // 64 KB
  const int tid = threadIdx.x;
  const int lane = tid & 63;
  const int w = tid >> 6;            // 0..7
  const int wm = w >> 2, wn = w & 3;

  // XCD-aware swizzle: 1024 blocks, 8 XCDs, chunk = 128 (bijective, 1024%8==0)
  const int orig = blockIdx.x;
  const int swz = (orig & 7) * 128 + (orig >> 3);
  const int gm0 = (swz >> 4) * BM2;  // 64 M-tiles
  const int gn0 = (swz & 15) * BN2;  // 16 N-tiles

  f32x4 acc[8][4];
#pragma unroll
  for (int i = 0; i < 8; ++i)
#pragma unroll
    for (int j = 0; j < 4; ++j) acc[i][j] = (f32x4){0.f, 0.f, 0.f, 0.f};

  // ---- staging addressing (pre-swizzled global source, linear LDS dest) ----
  // per stage call: 512 threads x 16B = 8KB = 64 rows; a 128-row half = 2 calls
  const int sr = (w << 3) + (lane >> 3);           // row 0..63 within a call
  const int sc = 8 * ((lane & 7) ^ (lane >> 3));   // swizzled source col (elems)
  const unsigned short* Agp = g_xb + (size_t)(gm0 + sr) * K_TOT + sc;
  const unsigned short* Bgp = g_wb + (size_t)(gn0 + sr) * K_TOT + sc;
  const int lr = (w << 3);                          // wave-uniform LDS row base

#define STAGE_A(tile, half) do {                                             \
    const int bi_ = (tile) & 1; const int kb_ = ((tile) & (NT2 - 1)) * BK2;  \
    __builtin_amdgcn_global_load_lds(                                        \
        (const AS1 void*)(Agp + (size_t)((half) * 128) * K_TOT + kb_),       \
        (AS3 void*)(&As[bi_][(half) * 128 + lr][0]), 16, 0, 0);              \
    __builtin_amdgcn_global_load_lds(                                        \
        (const AS1 void*)(Agp + (size_t)((half) * 128 + 64) * K_TOT + kb_),  \
        (AS3 void*)(&As[bi_][(half) * 128 + 64 + lr][0]), 16, 0, 0);         \
  } while (0)
#define STAGE_B(tile, half) do {                                             \
    const int bi_ = (tile) & 1; const int kb_ = ((tile) & (NT2 - 1)) * BK2;  \
    __builtin_amdgcn_global_load_lds(                                        \
        (const AS1 void*)(Bgp + (size_t)((half) * 128) * K_TOT + kb_),       \
        (AS3 void*)(&Bs[bi_][(half) * 128 + lr][0]), 16, 0, 0);              \
    __builtin_amdgcn_global_load_lds(                                        \
        (const AS1 void*)(Bgp + (size_t)((half) * 128 + 64) * K_TOT + kb_),  \
        (AS3 void*)(&Bs[bi_][(half) * 128 + 64 + lr][0]), 16, 0, 0);         \
  } while (0)

  // ---- fragment read addressing (XOR swizzle on byte column) ----
  const int r16 = lane & 15;
  const int kcb = (lane >> 4) << 4;        // 16B slot within 64B k-half
  const int xv = (r16 & 7) << 4;
  const char* Ab0 = (const char*)&As[0][wm * 128][0];
  const char* Bb0 = (const char*)&Bs[0][wn * 64][0];

  bf16x8 pA[4][2], pB0[2][2], pB1[2][2];

#define LD_A(qm, bi) do {                                                     \
    const char* ab_ = Ab0 + (bi) * BUFB + ((qm) * 64 + r16) * 128;            \
    _Pragma("unroll") for (int mi = 0; mi < 4; ++mi)                          \
      _Pragma("unroll") for (int sk = 0; sk < 2; ++sk)                        \
        pA[mi][sk] = *(const bf16x8*)(ab_ + mi * 16 * 128 +                   \
                                      ((sk * 64 + kcb) ^ xv));                \
  } while (0)
#define LD_B(P, qn, bi) do {                                                  \
    const char* bb_ = Bb0 + (bi) * BUFB + ((qn) * 32 + r16) * 128;            \
    _Pragma("unroll") for (int nf = 0; nf < 2; ++nf)                          \
      _Pragma("unroll") for (int sk = 0; sk < 2; ++sk)                        \
        P[nf][sk] = *(const bf16x8*)(bb_ + nf * 16 * 128 +                    \
                                     ((sk * 64 + kcb) ^ xv));                 \
  } while (0)
#define MFMA_Q(qm, qn, P) do {                                                \
    __builtin_amdgcn_s_setprio(1);                                            \
    _Pragma("unroll") for (int mi = 0; mi < 4; ++mi)                          \
      _Pragma("unroll") for (int nf = 0; nf < 2; ++nf)                        \
        _Pragma("unroll") for (int sk = 0; sk < 2; ++sk)                      \
          acc[(qm) * 4 + mi][(qn) * 2 + nf] =                                 \
              __builtin_amdgcn_mfma_f32_16x16x32_bf16(                        \
                  pA[mi][sk], P[nf][sk], acc[(qm) * 4 + mi][(qn) * 2 + nf],   \
                  0, 0, 0);                                                   \
    __builtin_amdgcn_s_setprio(0);                                            \
  } while (0)
#define BAR() __builtin_amdgcn_s_barrier()
#define WLG() asm volatile("s_waitcnt lgkmcnt(0)" ::: "memory")
#define WVM4() asm volatile("s_waitcnt vmcnt(4)" ::: "memory")

  // prologue: tile0 fully + tile1 B halves; vmcnt(4) leaves tile1-B in flight
  STAGE_B(0, 0); STAGE_B(0, 1); STAGE_A(0, 0); STAGE_A(0, 1);
  STAGE_B(1, 0); STAGE_B(1, 1);
  WVM4();
  BAR();

  for (int it = 0; it < NT2 / 2; ++it) {
    const int T = 2 * it;
    // ---- K-tile T (buf0) ----
    // ph1
    LD_A(0, 0); LD_B(pB0, 0, 0);
    STAGE_A(T + 1, 0);
    BAR(); WLG();
    MFMA_Q(0, 0, pB0);
    BAR();
    // ph2
    LD_B(pB1, 1, 0);
    STAGE_A(T + 1, 1);
    BAR(); WLG();
    MFMA_Q(0, 1, pB1);
    BAR();
    // ph3
    LD_A(1, 0);
    STAGE_B(T + 2, 0);
    BAR(); WLG();
    MFMA_Q(1, 1, pB1);
    BAR();
    // ph4 (no ds_reads; vmcnt proves tile T+1 landed)
    STAGE_B(T + 2, 1);
    WVM4();
    BAR();
    MFMA_Q(1, 0, pB0);
    BAR();
    // ---- K-tile T+1 (buf1) ----
    // ph5
    LD_A(0, 1); LD_B(pB0, 0, 1);
    STAGE_A(T + 2, 0);
    BAR(); WLG();
    MFMA_Q(0, 0, pB0);
    BAR();
    // ph6
    LD_B(pB1, 1, 1);
    STAGE_A(T + 2, 1);
    BAR(); WLG();
    MFMA_Q(0, 1, pB1);
    BAR();
    // ph7
    LD_A(1, 1);
    STAGE_B(T + 3, 0);
    BAR(); WLG();
    MFMA_Q(1, 1, pB1);
    BAR();
    // ph8 (vmcnt proves tile T+2 landed)
    STAGE_B(T + 3, 1);
    WVM4();
    BAR();
    MFMA_Q(1, 0, pB0);
    BAR();
  }

  // C/D layout (m89-verified): col = lane&15, row = (lane>>4)*4 + reg.
  // Quadrant split aligns with linear frag index: row offset = mi_g*16.
  const int cm0 = gm0 + wm * 128 + (lane >> 4) * 4;
  const int cn0 = gn0 + wn * 64 + (lane & 15);
#pragma unroll
  for (int mi = 0; mi < 8; ++mi)
#pragma unroll
    for (int nf = 0; nf < 4; ++nf)
#pragma unroll
      for (int r = 0; r < 4; ++r)
        out[(size_t)(cm0 + mi * 16 + r) * N_TOT + cn0 + nf * 16] = acc[mi][nf][r];
}

extern "C" void kernel_launch(void* const* d_in, const int* in_sizes, int n_in,
                              void* d_out, int out_size, void* d_ws, size_t ws_size,
                              hipStream_t stream) {
  const float* x  = (const float*)d_in[0];
  const float* wt = (const float*)d_in[1];
  const float* gr = (const float*)d_in[2];
  const void*  mk = d_in[3];
  const int*   nd = (const int*)d_in[4];
  (void)d_ws; (void)ws_size; (void)in_sizes; (void)n_in; (void)out_size;

  ctl_reset<<<1, 256, 0, stream>>>();
  mask_popcnt<<<512, 256, 0, stream>>>((const unsigned int*)mk);
  sel_init<<<1, 1, 0, stream>>>(nd);

  const int shifts[5] = {44, 32, 24, 12, 0};
  const int nbits[5]  = {12, 12, 8, 12, 12};

  for (int p = 0; p < 5; ++p) {   // drop: k smallest |w| (global)
    hist_pass<0><<<1024, 256, 0, stream>>>(wt, shifts[p], nbits[p]);
    select_pass<0><<<1, 256, 0, stream>>>(shifts[p], nbits[p]);
  }
  build_elig<<<NELEM / 4 / 256, 256, 0, stream>>>(wt, mk);
  for (int p = 0; p < 5; ++p) {   // grow: k largest |grad| among eligible
    hist_pass<1><<<1024, 256, 0, stream>>>(gr, shifts[p], nbits[p]);
    select_pass<1><<<1, 256, 0, stream>>>(shifts[p], nbits[p]);
  }
  build_wb<<<NELEM / 4 / 256, 256, 0, stream>>>(wt, gr);
  convert_x<<<(M_TOT * K_TOT / 4) / 256, 256, 0, stream>>>(x);
  gemm_kernel<<<1024, 512, 0, stream>>>((float*)d_out);
}